// Round 5
// baseline (271.424 us; speedup 1.0000x reference)
//
#include <hip/hip_runtime.h>
#include <hip/hip_bf16.h>

#define NN 10000
#define NE 320000

// ---------------- GEMM: C = act(A[MxK] @ B[KxN] + bias) ----------------
// 256 threads, 64x64 block tile, 4x4 micro-tile per thread. BK=32.
// ACT: 0 = none, 1 = tanh, 2 = sigmoid(tanh(x)). BIAS: add bias vector.
template<int ACT, bool BIAS, int K, int N>
__global__ __launch_bounds__(256) void gemm_kernel(
    const float* __restrict__ A, const float* __restrict__ B,
    const float* __restrict__ bias, float* __restrict__ C, int M) {
  __shared__ float As[64][33];   // [row][k], pad->33
  __shared__ float Bs[32][68];   // [k][col], pad->68: 16B-aligned float4 reads
  const int tid = threadIdx.x;
  const int tx = tid & 15;        // col group
  const int ty = tid >> 4;        // row group
  const int row0 = blockIdx.x * 64;
  const int col0 = blockIdx.y * 64;

  float acc[4][4];
#pragma unroll
  for (int i = 0; i < 4; i++)
#pragma unroll
    for (int j = 0; j < 4; j++) acc[i][j] = 0.f;

  for (int k0 = 0; k0 < K; k0 += 32) {
    // stage A tile (64 rows x 32 k), coalesced on k
#pragma unroll
    for (int idx = tid; idx < 64 * 32; idx += 256) {
      int r = idx >> 5, k = idx & 31;
      int row = row0 + r;
      As[r][k] = (row < M) ? A[row * K + k0 + k] : 0.f;
    }
    // stage B tile (32 k x 64 cols), coalesced on c
#pragma unroll
    for (int idx = tid; idx < 32 * 64; idx += 256) {
      int k = idx >> 6, c = idx & 63;
      Bs[k][c] = B[(k0 + k) * N + col0 + c];
    }
    __syncthreads();
#pragma unroll
    for (int k = 0; k < 32; k++) {
      float a0 = As[ty * 4 + 0][k];
      float a1 = As[ty * 4 + 1][k];
      float a2 = As[ty * 4 + 2][k];
      float a3 = As[ty * 4 + 3][k];
      float4 b = *(const float4*)&Bs[k][tx * 4];
      acc[0][0] = fmaf(a0, b.x, acc[0][0]);
      acc[0][1] = fmaf(a0, b.y, acc[0][1]);
      acc[0][2] = fmaf(a0, b.z, acc[0][2]);
      acc[0][3] = fmaf(a0, b.w, acc[0][3]);
      acc[1][0] = fmaf(a1, b.x, acc[1][0]);
      acc[1][1] = fmaf(a1, b.y, acc[1][1]);
      acc[1][2] = fmaf(a1, b.z, acc[1][2]);
      acc[1][3] = fmaf(a1, b.w, acc[1][3]);
      acc[2][0] = fmaf(a2, b.x, acc[2][0]);
      acc[2][1] = fmaf(a2, b.y, acc[2][1]);
      acc[2][2] = fmaf(a2, b.z, acc[2][2]);
      acc[2][3] = fmaf(a2, b.w, acc[2][3]);
      acc[3][0] = fmaf(a3, b.x, acc[3][0]);
      acc[3][1] = fmaf(a3, b.y, acc[3][1]);
      acc[3][2] = fmaf(a3, b.z, acc[3][2]);
      acc[3][3] = fmaf(a3, b.w, acc[3][3]);
    }
    __syncthreads();
  }

  float4 bias4 = make_float4(0.f, 0.f, 0.f, 0.f);
  if (BIAS) bias4 = *(const float4*)&bias[col0 + tx * 4];
#pragma unroll
  for (int i = 0; i < 4; i++) {
    int row = row0 + ty * 4 + i;
    if (row < M) {
      float4 v;
      v.x = acc[i][0] + bias4.x;
      v.y = acc[i][1] + bias4.y;
      v.z = acc[i][2] + bias4.z;
      v.w = acc[i][3] + bias4.w;
      if (ACT == 1) {
        v.x = tanhf(v.x); v.y = tanhf(v.y); v.z = tanhf(v.z); v.w = tanhf(v.w);
      } else if (ACT == 2) {
        v.x = 1.f / (1.f + expf(-tanhf(v.x)));
        v.y = 1.f / (1.f + expf(-tanhf(v.y)));
        v.z = 1.f / (1.f + expf(-tanhf(v.z)));
        v.w = 1.f / (1.f + expf(-tanhf(v.w)));
      }
      *(float4*)&C[row * N + col0 + tx * 4] = v;
    }
  }
}

// ---------------- CSR construction ----------------
__global__ void count_kernel(const int* __restrict__ dst, int* __restrict__ deg, int n) {
  int i = blockIdx.x * blockDim.x + threadIdx.x;
  if (i < n) atomicAdd(&deg[dst[i]], 1);
}

// single-block exclusive scan of deg -> offs (and a cursor copy)
__global__ __launch_bounds__(512) void scan_kernel(
    const int* __restrict__ deg, int* __restrict__ offs,
    int* __restrict__ cursor, int n) {
  __shared__ int buf[512];
  __shared__ int carry_s;
  if (threadIdx.x == 0) carry_s = 0;
  __syncthreads();
  for (int base = 0; base < n; base += 512) {
    int i = base + threadIdx.x;
    int v = (i < n) ? deg[i] : 0;
    buf[threadIdx.x] = v;
    __syncthreads();
    int sum = v;
    for (int off = 1; off < 512; off <<= 1) {
      int t = 0;
      if ((int)threadIdx.x >= off) t = buf[threadIdx.x - off];
      __syncthreads();
      sum += t;
      buf[threadIdx.x] = sum;
      __syncthreads();
    }
    int carry = carry_s;
    if (i < n) {
      int ex = carry + sum - v;   // exclusive prefix
      offs[i] = ex;
      cursor[i] = ex;
    }
    __syncthreads();
    if (threadIdx.x == 511) carry_s = carry + buf[511];
    __syncthreads();
  }
}

__global__ void fill_kernel(const int* __restrict__ src, const int* __restrict__ dst,
                            int* __restrict__ cursor, int* __restrict__ csr, int n) {
  int i = blockIdx.x * blockDim.x + threadIdx.x;
  if (i < n) {
    int d = dst[i];
    int pos = atomicAdd(&cursor[d], 1);
    csr[pos] = src[i];
  }
}

// ---------------- segment mean over PROJECTED rows (128 cols) + bias, writes out
// one wave (64 lanes) per node, float2/lane = 128 cols; 512B coalesced per edge
__global__ __launch_bounds__(256) void aggregate_kernel(
    const float* __restrict__ hproj, const int* __restrict__ csr,
    const int* __restrict__ offs, const int* __restrict__ deg,
    const float* __restrict__ bo, float* __restrict__ out, int n_nodes) {
  int wave = threadIdx.x >> 6;
  int lane = threadIdx.x & 63;
  int node = blockIdx.x * 4 + wave;
  if (node >= n_nodes) return;
  int start = offs[node];
  int d = deg[node];
  const float2* h2 = (const float2*)hproj;
  float2 acc = make_float2(0.f, 0.f);
  int t = 0;
  for (; t + 4 <= d; t += 4) {
    int s0 = csr[start + t + 0];
    int s1 = csr[start + t + 1];
    int s2 = csr[start + t + 2];
    int s3 = csr[start + t + 3];
    float2 v0 = h2[s0 * 64 + lane];
    float2 v1 = h2[s1 * 64 + lane];
    float2 v2 = h2[s2 * 64 + lane];
    float2 v3 = h2[s3 * 64 + lane];
    acc.x += (v0.x + v1.x) + (v2.x + v3.x);
    acc.y += (v0.y + v1.y) + (v2.y + v3.y);
  }
  for (; t < d; t++) {
    int s = csr[start + t];
    float2 v = h2[s * 64 + lane];
    acc.x += v.x; acc.y += v.y;
  }
  float scale = 1.f / fmaxf((float)d, 1.f);
  float2 b = ((const float2*)bo)[lane];
  float2 o = make_float2(fmaf(acc.x, scale, b.x), fmaf(acc.y, scale, b.y));
  ((float2*)out)[node * 64 + lane] = o;
}

extern "C" void kernel_launch(void* const* d_in, const int* in_sizes, int n_in,
                              void* d_out, int out_size, void* d_ws, size_t ws_size,
                              hipStream_t stream) {
  const float* X    = (const float*)d_in[0];   // [10000,128]
  const int*   esrc = (const int*)d_in[1];     // [320000]
  const int*   edst = (const int*)d_in[2];     // [320000]
  const float* W1   = (const float*)d_in[3];   // [128,256]
  const float* b1   = (const float*)d_in[4];
  const float* W2   = (const float*)d_in[5];   // [256,256]
  const float* b2   = (const float*)d_in[6];
  const float* Wo   = (const float*)d_in[7];   // [256,128]
  const float* bo   = (const float*)d_in[8];
  float* out = (float*)d_out;                  // [10000,128]

  // Workspace (floats first -> 16B alignment). h1 dead after GEMM2 -> hproj reuses it.
  size_t needed = (size_t)NN * 256 * 4 * 2 + (size_t)NN * 4 * 3 + (size_t)NE * 4;
  if (ws_size < needed) return;  // fail validation cleanly rather than fault

  char* ws = (char*)d_ws;
  float* h1     = (float*)ws; ws += (size_t)NN * 256 * 4;   // 10.24 MB
  float* hidden = (float*)ws; ws += (size_t)NN * 256 * 4;   // 10.24 MB
  float* hproj  = h1;                                       // [10000,128], reuse
  int*   deg    = (int*)ws;   ws += (size_t)NN * 4;
  int*   offs   = (int*)ws;   ws += (size_t)NN * 4;
  int*   cursor = (int*)ws;   ws += (size_t)NN * 4;
  int*   csr    = (int*)ws;   ws += (size_t)NE * 4;

  // deg must start at zero (ws is poisoned each call)
  hipMemsetAsync(deg, 0, NN * sizeof(int), stream);

  // CSR build (independent of the MLP)
  count_kernel<<<(NE + 255) / 256, 256, 0, stream>>>(edst, deg, NE);
  scan_kernel<<<1, 512, 0, stream>>>(deg, offs, cursor, NN);
  fill_kernel<<<(NE + 255) / 256, 256, 0, stream>>>(esrc, edst, cursor, csr, NE);

  // MLP encoder
  gemm_kernel<1, true, 128, 256><<<dim3(157, 4), 256, 0, stream>>>(X,  W1, b1, h1,     NN);
  gemm_kernel<2, true, 256, 256><<<dim3(157, 4), 256, 0, stream>>>(h1, W2, b2, hidden, NN);

  // project BEFORE aggregating: mean(hidden) @ Wo == mean(hidden @ Wo)  (linear)
  gemm_kernel<0, false, 256, 128><<<dim3(157, 2), 256, 0, stream>>>(hidden, Wo, nullptr, hproj, NN);

  // neighbor mean over projected rows + fused bo, writes d_out directly
  aggregate_kernel<<<(NN + 3) / 4, 256, 0, stream>>>(hproj, csr, offs, deg, bo, out, NN);
}

// Round 7
// 185.189 us; speedup vs baseline: 1.4657x; 1.4657x over previous
//
#include <hip/hip_runtime.h>
#include <hip/hip_bf16.h>

#define NN 10000
#define NE 320000

typedef __attribute__((ext_vector_type(8))) short bf16x8;     // 8 bf16 (4 VGPRs) - MFMA A/B frag
typedef __attribute__((ext_vector_type(4))) float f32x4;      // 4 fp32 - MFMA C/D frag
typedef __attribute__((ext_vector_type(8))) unsigned short ushort8;

// split fp32 -> bf16 hi + bf16 lo (a ~= hi + lo, error ~2^-16 relative)
__device__ inline void split_bf16(float a, unsigned short& hi, unsigned short& lo) {
  union { float f; unsigned int u; } v; v.f = a;
  hi = (unsigned short)(v.u >> 16);                 // truncate
  union { float f; unsigned int u; } h; h.u = (unsigned int)hi << 16;
  float r = a - h.f;                                // exact
  union { float f; unsigned int u; } w; w.f = r;
  lo = (unsigned short)(w.u >> 16);
}

// ---------------- convert X: fp32 [NN,128] -> hi/lo bf16 ----------------
__global__ __launch_bounds__(256) void convertx_kernel(
    const float* __restrict__ X, unsigned short* __restrict__ Xhi,
    unsigned short* __restrict__ Xlo) {
  int i = blockIdx.x * 256 + threadIdx.x;   // NN*128 = 1,280,000 exact multiple of 256
  float a = X[i];
  unsigned short h, l; split_bf16(a, h, l);
  Xhi[i] = h; Xlo[i] = l;
}

// ---------------- weight prep: W[K][N] fp32 -> Wt_hi/lo[N][K] bf16 ----------------
template<int K, int N>
__global__ __launch_bounds__(256) void prepw_kernel(
    const float* __restrict__ W, unsigned short* __restrict__ Thi,
    unsigned short* __restrict__ Tlo) {
  int e = blockIdx.x * 256 + threadIdx.x;
  if (e >= K * N) return;
  int k = e / N, n = e % N;                 // N is 128/256 -> shifts
  unsigned short h, l; split_bf16(W[e], h, l);
  Thi[n * K + k] = h; Tlo[n * K + k] = l;
}

// ---------------- MFMA GEMM: C = act(A[MxK] @ B[KxN] + bias) ----------------
// A given as hi/lo bf16 [M][K]; B given pre-transposed hi/lo bf16 [N][K].
// Split product: A*B ~= Ah*Bh + Ah*Bl + Al*Bh  (fp32-accumulated MFMA).
// Block: 256 thr = 4 waves (2x2), tile 64x64, BK=64, wave tile 32x32 (2x2 frags
// of 16x16x32). LDS XOR-swizzled ((row&7) on 16B-chunk index) both sides.
// ACT: 0 none, 1 tanh, 2 sigmoid(tanh). OUTM: 0 = fp32 C, 1 = bf16 hi/lo pair.
template<int ACT, bool BIAS_, int OUTM, int K, int N>
__global__ __launch_bounds__(256) void mfma_gemm(
    const unsigned short* __restrict__ Ahi_g, const unsigned short* __restrict__ Alo_g,
    const unsigned short* __restrict__ Bthi_g, const unsigned short* __restrict__ Btlo_g,
    const float* __restrict__ bias, float* __restrict__ Cf,
    unsigned short* __restrict__ Chi, unsigned short* __restrict__ Clo, int M) {
  __shared__ unsigned short Ah[64 * 64], Al[64 * 64], Bh[64 * 64], Bl[64 * 64]; // 32 KB

  const int tid = threadIdx.x;
  const int lane = tid & 63;
  const int wid = tid >> 6;
  const int wr = wid >> 1, wc = wid & 1;          // 2x2 wave grid over 64x64 tile
  const int row0 = blockIdx.x * 64;
  const int col0 = blockIdx.y * 64;

  f32x4 acc[2][2];
#pragma unroll
  for (int m = 0; m < 2; m++)
#pragma unroll
    for (int n = 0; n < 2; n++) acc[m][n] = (f32x4){0.f, 0.f, 0.f, 0.f};

  for (int kt = 0; kt < K / 64; ++kt) {
    // ---- stage 4 tiles (each 64x64 bf16 = 8KB = 512 x 16B chunks) ----
#pragma unroll
    for (int it = 0; it < 2; ++it) {
      int c = it * 256 + tid;
      int r = c >> 3, cj = c & 7;                 // LDS row, 16B chunk within row
      int dj = (cj ^ (r & 7)) * 8;                // XOR-swizzled chunk slot
      int grow = row0 + r; if (grow > M - 1) grow = M - 1;   // clamp tail rows
      size_t ga = (size_t)grow * K + kt * 64 + cj * 8;
      *(ushort8*)&Ah[r * 64 + dj] = *(const ushort8*)&Ahi_g[ga];
      *(ushort8*)&Al[r * 64 + dj] = *(const ushort8*)&Alo_g[ga];
      size_t gb = (size_t)(col0 + r) * K + kt * 64 + cj * 8; // N multiple of 64
      *(ushort8*)&Bh[r * 64 + dj] = *(const ushort8*)&Bthi_g[gb];
      *(ushort8*)&Bl[r * 64 + dj] = *(const ushort8*)&Btlo_g[gb];
    }
    __syncthreads();
    // ---- 2 MFMA K-steps of 32 ----
#pragma unroll
    for (int kk = 0; kk < 2; ++kk) {
      bf16x8 aH[2], aL[2], bH[2], bL[2];
#pragma unroll
      for (int m = 0; m < 2; m++) {
        int row = wr * 32 + m * 16 + (lane & 15);
        int ch = (kk * 4 + (lane >> 4)) ^ (row & 7);
        aH[m] = *(const bf16x8*)&Ah[row * 64 + ch * 8];
        aL[m] = *(const bf16x8*)&Al[row * 64 + ch * 8];
      }
#pragma unroll
      for (int n = 0; n < 2; n++) {
        int col = wc * 32 + n * 16 + (lane & 15);
        int ch = (kk * 4 + (lane >> 4)) ^ (col & 7);
        bH[n] = *(const bf16x8*)&Bh[col * 64 + ch * 8];
        bL[n] = *(const bf16x8*)&Bl[col * 64 + ch * 8];
      }
#pragma unroll
      for (int m = 0; m < 2; m++)
#pragma unroll
        for (int n = 0; n < 2; n++) {
          acc[m][n] = __builtin_amdgcn_mfma_f32_16x16x32_bf16(aH[m], bH[n], acc[m][n], 0, 0, 0);
          acc[m][n] = __builtin_amdgcn_mfma_f32_16x16x32_bf16(aH[m], bL[n], acc[m][n], 0, 0, 0);
          acc[m][n] = __builtin_amdgcn_mfma_f32_16x16x32_bf16(aL[m], bH[n], acc[m][n], 0, 0, 0);
        }
    }
    __syncthreads();
  }

  // ---- epilogue: bias + activation; write fp32 or fused bf16 hi/lo pair ----
  // C/D frag layout (HW-verified): col = lane&15, row = (lane>>4)*4 + j
#pragma unroll
  for (int m = 0; m < 2; m++)
#pragma unroll
    for (int n = 0; n < 2; n++) {
      int col = col0 + wc * 32 + n * 16 + (lane & 15);
      float bv = BIAS_ ? bias[col] : 0.f;
#pragma unroll
      for (int j = 0; j < 4; j++) {
        int row = row0 + wr * 32 + m * 16 + (lane >> 4) * 4 + j;
        if (row < M) {
          float v = acc[m][n][j] + bv;
          if (ACT == 1) v = tanhf(v);
          else if (ACT == 2) v = 1.f / (1.f + expf(-tanhf(v)));
          if (OUTM == 0) {
            Cf[(size_t)row * N + col] = v;
          } else {
            unsigned short h, l; split_bf16(v, h, l);
            Chi[(size_t)row * N + col] = h;
            Clo[(size_t)row * N + col] = l;
          }
        }
      }
    }
}

// ---------------- CSR construction ----------------
__global__ void count_kernel(const int* __restrict__ dst, int* __restrict__ deg, int n) {
  int i = blockIdx.x * blockDim.x + threadIdx.x;
  if (i < n) atomicAdd(&deg[dst[i]], 1);
}

// 1-block exclusive scan: 1024 thr x 10 nodes, shfl wave-scan, 3 barriers
__global__ __launch_bounds__(1024) void scan_kernel(
    const int* __restrict__ deg, int* __restrict__ offs, int* __restrict__ cursor) {
  __shared__ int wsum[16];
  int t = threadIdx.x;
  int base = t * 10;
  int loc[10];
  int s = 0;
  if (base < NN) {
#pragma unroll
    for (int i = 0; i < 10; i++) {
      int idx = base + i;
      int v = (idx < NN) ? deg[idx] : 0;
      loc[i] = s; s += v;
    }
  }
  int lane = t & 63, w = t >> 6;
  int incl = s;
  for (int off = 1; off < 64; off <<= 1) {
    int u = __shfl_up(incl, off, 64);
    if (lane >= off) incl += u;
  }
  if (lane == 63) wsum[w] = incl;
  __syncthreads();
  if (t == 0) {
    int c = 0;
#pragma unroll
    for (int i = 0; i < 16; i++) { int v = wsum[i]; wsum[i] = c; c += v; }
  }
  __syncthreads();
  int ex = wsum[w] + incl - s;   // exclusive prefix for this thread's chunk
  if (base < NN) {
#pragma unroll
    for (int i = 0; i < 10; i++) {
      int idx = base + i;
      if (idx < NN) { int o = ex + loc[i]; offs[idx] = o; cursor[idx] = o; }
    }
  }
}

__global__ void fill_kernel(const int* __restrict__ src, const int* __restrict__ dst,
                            int* __restrict__ cursor, int* __restrict__ csr, int n) {
  int i = blockIdx.x * blockDim.x + threadIdx.x;
  if (i < n) {
    int d = dst[i];
    int pos = atomicAdd(&cursor[d], 1);
    csr[pos] = src[i];
  }
}

// ---------------- segment mean over PROJECTED rows (128 cols) + bias -> out
__global__ __launch_bounds__(256) void aggregate_kernel(
    const float* __restrict__ hproj, const int* __restrict__ csr,
    const int* __restrict__ offs, const int* __restrict__ deg,
    const float* __restrict__ bo, float* __restrict__ out, int n_nodes) {
  int wave = threadIdx.x >> 6;
  int lane = threadIdx.x & 63;
  int node = blockIdx.x * 4 + wave;
  if (node >= n_nodes) return;
  int start = offs[node];
  int d = deg[node];
  const float2* h2 = (const float2*)hproj;
  float2 acc = make_float2(0.f, 0.f);
  int t = 0;
  for (; t + 4 <= d; t += 4) {
    int s0 = csr[start + t + 0];
    int s1 = csr[start + t + 1];
    int s2 = csr[start + t + 2];
    int s3 = csr[start + t + 3];
    float2 v0 = h2[s0 * 64 + lane];
    float2 v1 = h2[s1 * 64 + lane];
    float2 v2 = h2[s2 * 64 + lane];
    float2 v3 = h2[s3 * 64 + lane];
    acc.x += (v0.x + v1.x) + (v2.x + v3.x);
    acc.y += (v0.y + v1.y) + (v2.y + v3.y);
  }
  for (; t < d; t++) {
    int s = csr[start + t];
    float2 v = h2[s * 64 + lane];
    acc.x += v.x; acc.y += v.y;
  }
  float scale = 1.f / fmaxf((float)d, 1.f);
  float2 b = ((const float2*)bo)[lane];
  float2 o = make_float2(fmaf(acc.x, scale, b.x), fmaf(acc.y, scale, b.y));
  ((float2*)out)[node * 64 + lane] = o;
}

extern "C" void kernel_launch(void* const* d_in, const int* in_sizes, int n_in,
                              void* d_out, int out_size, void* d_ws, size_t ws_size,
                              hipStream_t stream) {
  const float* X    = (const float*)d_in[0];   // [10000,128]
  const int*   esrc = (const int*)d_in[1];     // [320000]
  const int*   edst = (const int*)d_in[2];     // [320000]
  const float* W1   = (const float*)d_in[3];   // [128,256]
  const float* b1   = (const float*)d_in[4];
  const float* W2   = (const float*)d_in[5];   // [256,256]
  const float* b2   = (const float*)d_in[6];
  const float* Wo   = (const float*)d_in[7];   // [256,128]
  const float* bo   = (const float*)d_in[8];
  float* out = (float*)d_out;                  // [10000,128]

  // ---- workspace layout (~22.4 MB; round-5 layout of 21.9 MB fit) ----
  // regionA (10.24MB): X hi/lo pair (first 5.12MB), then reused for hid pair
  // regionB (10.24MB): h1 hi/lo pair, then reused for hproj fp32
  char* p = (char*)d_ws;
  size_t needed = (size_t)NN * 256 * 4 * 2                     // regionA + regionB
                + (size_t)(32768 + 65536 + 32768) * 2 * 2      // weight hi/lo pairs
                + (size_t)(3 * NN + NE) * 4;                   // deg/offs/cursor/csr
  if (ws_size < needed) return;

  unsigned short* regA  = (unsigned short*)p;
  unsigned short* Xhi   = regA;                                // NN*128
  unsigned short* Xlo   = regA + (size_t)NN * 128;
  unsigned short* hidhi = regA;                                // NN*256 (X dead after GEMM1)
  unsigned short* hidlo = regA + (size_t)NN * 256;
  p += (size_t)NN * 256 * 4;
  unsigned short* h1hi  = (unsigned short*)p;                  // NN*256
  unsigned short* h1lo  = h1hi + (size_t)NN * 256;
  float*          hproj = (float*)h1hi;                        // NN*128 f32 (h1 dead after GEMM2)
  p += (size_t)NN * 256 * 4;
  unsigned short* W1thi = (unsigned short*)p; p += 32768 * 2;  // [256][128]
  unsigned short* W1tlo = (unsigned short*)p; p += 32768 * 2;
  unsigned short* W2thi = (unsigned short*)p; p += 65536 * 2;  // [256][256]
  unsigned short* W2tlo = (unsigned short*)p; p += 65536 * 2;
  unsigned short* Wothi = (unsigned short*)p; p += 32768 * 2;  // [128][256]
  unsigned short* Wotlo = (unsigned short*)p; p += 32768 * 2;
  int* deg    = (int*)p; p += (size_t)NN * 4;
  int* offs   = (int*)p; p += (size_t)NN * 4;
  int* cursor = (int*)p; p += (size_t)NN * 4;
  int* csr    = (int*)p; p += (size_t)NE * 4;

  hipMemsetAsync(deg, 0, NN * sizeof(int), stream);

  // CSR build
  count_kernel<<<(NE + 255) / 256, 256, 0, stream>>>(edst, deg, NE);
  scan_kernel<<<1, 1024, 0, stream>>>(deg, offs, cursor);
  fill_kernel<<<(NE + 255) / 256, 256, 0, stream>>>(esrc, edst, cursor, csr, NE);

  // input/weight split-bf16 prep
  convertx_kernel<<<NN * 128 / 256, 256, 0, stream>>>(X, Xhi, Xlo);
  prepw_kernel<128, 256><<<(128 * 256 + 255) / 256, 256, 0, stream>>>(W1, W1thi, W1tlo);
  prepw_kernel<256, 256><<<(256 * 256 + 255) / 256, 256, 0, stream>>>(W2, W2thi, W2tlo);
  prepw_kernel<256, 128><<<(256 * 128 + 255) / 256, 256, 0, stream>>>(Wo, Wothi, Wotlo);

  // MLP encoder on MFMA (split-bf16, fp32-equivalent accuracy)
  mfma_gemm<1, true, 1, 128, 256><<<dim3(157, 4), 256, 0, stream>>>(
      Xhi, Xlo, W1thi, W1tlo, b1, nullptr, h1hi, h1lo, NN);
  mfma_gemm<2, true, 1, 256, 256><<<dim3(157, 4), 256, 0, stream>>>(
      h1hi, h1lo, W2thi, W2tlo, b2, nullptr, hidhi, hidlo, NN);
  // project BEFORE aggregating (mean is linear); fp32 output for aggregate
  mfma_gemm<0, false, 0, 256, 128><<<dim3(157, 2), 256, 0, stream>>>(
      hidhi, hidlo, Wothi, Wotlo, nullptr, hproj, nullptr, nullptr, NN);

  // neighbor mean over projected rows + fused bo -> d_out
  aggregate_kernel<<<(NN + 3) / 4, 256, 0, stream>>>(hproj, csr, offs, deg, bo, out, NN);
}

// Round 8
// 174.604 us; speedup vs baseline: 1.5545x; 1.0606x over previous
//
#include <hip/hip_runtime.h>
#include <hip/hip_bf16.h>

#define NN 10000
#define NE 320000

typedef __attribute__((ext_vector_type(8))) short bf16x8;     // 8 bf16 (4 VGPRs) - MFMA A/B frag
typedef __attribute__((ext_vector_type(4))) float f32x4;      // 4 fp32 - MFMA C/D frag
typedef __attribute__((ext_vector_type(8))) unsigned short ushort8;

// split fp32 -> bf16 hi + bf16 lo (a ~= hi + lo, error ~2^-16 relative)
__device__ inline void split_bf16(float a, unsigned short& hi, unsigned short& lo) {
  union { float f; unsigned int u; } v; v.f = a;
  hi = (unsigned short)(v.u >> 16);                 // truncate
  union { float f; unsigned int u; } h; h.u = (unsigned int)hi << 16;
  float r = a - h.f;                                // exact
  union { float f; unsigned int u; } w; w.f = r;
  lo = (unsigned short)(w.u >> 16);
}

// ---------------- fused prep: deg=0, X split, 3 weight transpose+splits -------
// grid = 1250 x 256 = 320000 threads (1 float4 of X per thread)
__global__ __launch_bounds__(256) void prep_kernel(
    const float* __restrict__ X, unsigned short* __restrict__ Xhi,
    unsigned short* __restrict__ Xlo,
    const float* __restrict__ W1, unsigned short* __restrict__ W1thi,
    unsigned short* __restrict__ W1tlo,
    const float* __restrict__ W2, unsigned short* __restrict__ W2thi,
    unsigned short* __restrict__ W2tlo,
    const float* __restrict__ Wo, unsigned short* __restrict__ Wothi,
    unsigned short* __restrict__ Wotlo,
    int* __restrict__ deg) {
  int i = blockIdx.x * 256 + threadIdx.x;           // 0..319999

  // 1) zero deg (10000 ints = 2500 int4)
  if (i < 2500) ((int4*)deg)[i] = make_int4(0, 0, 0, 0);

  // 2) split X: 1,280,000 floats = 320,000 float4 (coalesced both sides)
  {
    float4 x = ((const float4*)X)[i];
    ushort4 h, l;
    split_bf16(x.x, h.x, l.x);
    split_bf16(x.y, h.y, l.y);
    split_bf16(x.z, h.z, l.z);
    split_bf16(x.w, h.w, l.w);
    ((ushort4*)Xhi)[i] = h;
    ((ushort4*)Xlo)[i] = l;
  }

  // 3) weight transpose+split, OUTPUT-coalesced (scattered 4B reads hit L2)
  if (i < 32768) {                                  // W1 [128][256] -> W1t [256][128]
    int n = i >> 7, k = i & 127;
    unsigned short h, l; split_bf16(W1[k * 256 + n], h, l);
    W1thi[i] = h; W1tlo[i] = l;
  }
  if (i < 65536) {                                  // W2 [256][256] -> W2t [256][256]
    int n = i >> 8, k = i & 255;
    unsigned short h, l; split_bf16(W2[k * 256 + n], h, l);
    W2thi[i] = h; W2tlo[i] = l;
  }
  if (i >= 65536 && i < 98304) {                    // Wo [256][128] -> Wot [128][256]
    int o = i - 65536;
    int n = o >> 8, k = o & 255;
    unsigned short h, l; split_bf16(Wo[k * 128 + n], h, l);
    Wothi[o] = h; Wotlo[o] = l;
  }
}

// ---------------- MFMA GEMM: C = act(A[MxK] @ B[KxN] + bias) ----------------
// A given as hi/lo bf16 [M][K]; B given pre-transposed hi/lo bf16 [N][K].
// Split product: A*B ~= Ah*Bh + Ah*Bl + Al*Bh  (fp32-accumulated MFMA).
// Block: 256 thr = 4 waves (2x2), tile 64x64, BK=64, wave tile 32x32 (2x2 frags
// of 16x16x32). LDS XOR-swizzled ((row&7) on 16B-chunk index) both sides.
// ACT: 0 none, 1 tanh, 2 sigmoid(tanh). OUTM: 0 = fp32 C, 1 = bf16 hi/lo pair.
template<int ACT, bool BIAS_, int OUTM, int K, int N>
__global__ __launch_bounds__(256) void mfma_gemm(
    const unsigned short* __restrict__ Ahi_g, const unsigned short* __restrict__ Alo_g,
    const unsigned short* __restrict__ Bthi_g, const unsigned short* __restrict__ Btlo_g,
    const float* __restrict__ bias, float* __restrict__ Cf,
    unsigned short* __restrict__ Chi, unsigned short* __restrict__ Clo, int M) {
  __shared__ unsigned short Ah[64 * 64], Al[64 * 64], Bh[64 * 64], Bl[64 * 64]; // 32 KB

  const int tid = threadIdx.x;
  const int lane = tid & 63;
  const int wid = tid >> 6;
  const int wr = wid >> 1, wc = wid & 1;          // 2x2 wave grid over 64x64 tile
  const int row0 = blockIdx.x * 64;
  const int col0 = blockIdx.y * 64;

  f32x4 acc[2][2];
#pragma unroll
  for (int m = 0; m < 2; m++)
#pragma unroll
    for (int n = 0; n < 2; n++) acc[m][n] = (f32x4){0.f, 0.f, 0.f, 0.f};

  for (int kt = 0; kt < K / 64; ++kt) {
    // ---- stage 4 tiles (each 64x64 bf16 = 8KB = 512 x 16B chunks) ----
#pragma unroll
    for (int it = 0; it < 2; ++it) {
      int c = it * 256 + tid;
      int r = c >> 3, cj = c & 7;                 // LDS row, 16B chunk within row
      int dj = (cj ^ (r & 7)) * 8;                // XOR-swizzled chunk slot
      int grow = row0 + r; if (grow > M - 1) grow = M - 1;   // clamp tail rows
      size_t ga = (size_t)grow * K + kt * 64 + cj * 8;
      *(ushort8*)&Ah[r * 64 + dj] = *(const ushort8*)&Ahi_g[ga];
      *(ushort8*)&Al[r * 64 + dj] = *(const ushort8*)&Alo_g[ga];
      size_t gb = (size_t)(col0 + r) * K + kt * 64 + cj * 8; // N multiple of 64
      *(ushort8*)&Bh[r * 64 + dj] = *(const ushort8*)&Bthi_g[gb];
      *(ushort8*)&Bl[r * 64 + dj] = *(const ushort8*)&Btlo_g[gb];
    }
    __syncthreads();
    // ---- 2 MFMA K-steps of 32 ----
#pragma unroll
    for (int kk = 0; kk < 2; ++kk) {
      bf16x8 aH[2], aL[2], bH[2], bL[2];
#pragma unroll
      for (int m = 0; m < 2; m++) {
        int row = wr * 32 + m * 16 + (lane & 15);
        int ch = (kk * 4 + (lane >> 4)) ^ (row & 7);
        aH[m] = *(const bf16x8*)&Ah[row * 64 + ch * 8];
        aL[m] = *(const bf16x8*)&Al[row * 64 + ch * 8];
      }
#pragma unroll
      for (int n = 0; n < 2; n++) {
        int col = wc * 32 + n * 16 + (lane & 15);
        int ch = (kk * 4 + (lane >> 4)) ^ (col & 7);
        bH[n] = *(const bf16x8*)&Bh[col * 64 + ch * 8];
        bL[n] = *(const bf16x8*)&Bl[col * 64 + ch * 8];
      }
#pragma unroll
      for (int m = 0; m < 2; m++)
#pragma unroll
        for (int n = 0; n < 2; n++) {
          acc[m][n] = __builtin_amdgcn_mfma_f32_16x16x32_bf16(aH[m], bH[n], acc[m][n], 0, 0, 0);
          acc[m][n] = __builtin_amdgcn_mfma_f32_16x16x32_bf16(aH[m], bL[n], acc[m][n], 0, 0, 0);
          acc[m][n] = __builtin_amdgcn_mfma_f32_16x16x32_bf16(aL[m], bH[n], acc[m][n], 0, 0, 0);
        }
    }
    __syncthreads();
  }

  // ---- epilogue: bias + activation; write fp32 or fused bf16 hi/lo pair ----
  // C/D frag layout (HW-verified): col = lane&15, row = (lane>>4)*4 + j
#pragma unroll
  for (int m = 0; m < 2; m++)
#pragma unroll
    for (int n = 0; n < 2; n++) {
      int col = col0 + wc * 32 + n * 16 + (lane & 15);
      float bv = BIAS_ ? bias[col] : 0.f;
#pragma unroll
      for (int j = 0; j < 4; j++) {
        int row = row0 + wr * 32 + m * 16 + (lane >> 4) * 4 + j;
        if (row < M) {
          float v = acc[m][n][j] + bv;
          if (ACT == 1) v = tanhf(v);
          else if (ACT == 2) v = 1.f / (1.f + expf(-tanhf(v)));
          if (OUTM == 0) {
            Cf[(size_t)row * N + col] = v;
          } else {
            unsigned short h, l; split_bf16(v, h, l);
            Chi[(size_t)row * N + col] = h;
            Clo[(size_t)row * N + col] = l;
          }
        }
      }
    }
}

// ---------------- CSR construction ----------------
__global__ void count_kernel(const int* __restrict__ dst, int* __restrict__ deg, int n) {
  int i = blockIdx.x * blockDim.x + threadIdx.x;
  if (i < n) atomicAdd(&deg[dst[i]], 1);
}

// 1-block exclusive scan: 1024 thr x 10 nodes, shfl wave-scan, 3 barriers
__global__ __launch_bounds__(1024) void scan_kernel(
    const int* __restrict__ deg, int* __restrict__ offs, int* __restrict__ cursor) {
  __shared__ int wsum[16];
  int t = threadIdx.x;
  int base = t * 10;
  int loc[10];
  int s = 0;
  if (base < NN) {
#pragma unroll
    for (int i = 0; i < 10; i++) {
      int idx = base + i;
      int v = (idx < NN) ? deg[idx] : 0;
      loc[i] = s; s += v;
    }
  }
  int lane = t & 63, w = t >> 6;
  int incl = s;
  for (int off = 1; off < 64; off <<= 1) {
    int u = __shfl_up(incl, off, 64);
    if (lane >= off) incl += u;
  }
  if (lane == 63) wsum[w] = incl;
  __syncthreads();
  if (t == 0) {
    int c = 0;
#pragma unroll
    for (int i = 0; i < 16; i++) { int v = wsum[i]; wsum[i] = c; c += v; }
  }
  __syncthreads();
  int ex = wsum[w] + incl - s;   // exclusive prefix for this thread's chunk
  if (base < NN) {
#pragma unroll
    for (int i = 0; i < 10; i++) {
      int idx = base + i;
      if (idx < NN) { int o = ex + loc[i]; offs[idx] = o; cursor[idx] = o; }
    }
  }
}

__global__ void fill_kernel(const int* __restrict__ src, const int* __restrict__ dst,
                            int* __restrict__ cursor, int* __restrict__ csr, int n) {
  int i = blockIdx.x * blockDim.x + threadIdx.x;
  if (i < n) {
    int d = dst[i];
    int pos = atomicAdd(&cursor[d], 1);
    csr[pos] = src[i];
  }
}

// ---------------- segment mean over PROJECTED rows (128 cols) + bias -> out
// one wave per node; 64 csr indices fetched per coalesced load, broadcast via
// shfl; gathers 8-deep in flight (csr latency off the critical path)
__global__ __launch_bounds__(256) void aggregate_kernel(
    const float* __restrict__ hproj, const int* __restrict__ csr,
    const int* __restrict__ offs, const int* __restrict__ deg,
    const float* __restrict__ bo, float* __restrict__ out, int n_nodes) {
  int wave = threadIdx.x >> 6;
  int lane = threadIdx.x & 63;
  int node = blockIdx.x * 4 + wave;
  if (node >= n_nodes) return;
  int start = offs[node];
  int d = deg[node];
  const float2* h2 = (const float2*)hproj;
  float2 acc0 = make_float2(0.f, 0.f), acc1 = make_float2(0.f, 0.f);
  for (int t0 = 0; t0 < d; t0 += 64) {
    int rem = d - t0; if (rem > 64) rem = 64;
    int idx = (lane < rem) ? csr[start + t0 + lane] : 0;  // one coalesced load / 64 edges
    int j = 0;
    for (; j + 8 <= rem; j += 8) {
      int s0 = __shfl(idx, j + 0), s1 = __shfl(idx, j + 1);
      int s2 = __shfl(idx, j + 2), s3 = __shfl(idx, j + 3);
      int s4 = __shfl(idx, j + 4), s5 = __shfl(idx, j + 5);
      int s6 = __shfl(idx, j + 6), s7 = __shfl(idx, j + 7);
      float2 v0 = h2[s0 * 64 + lane], v1 = h2[s1 * 64 + lane];
      float2 v2 = h2[s2 * 64 + lane], v3 = h2[s3 * 64 + lane];
      float2 v4 = h2[s4 * 64 + lane], v5 = h2[s5 * 64 + lane];
      float2 v6 = h2[s6 * 64 + lane], v7 = h2[s7 * 64 + lane];
      acc0.x += (v0.x + v1.x) + (v2.x + v3.x);
      acc0.y += (v0.y + v1.y) + (v2.y + v3.y);
      acc1.x += (v4.x + v5.x) + (v6.x + v7.x);
      acc1.y += (v4.y + v5.y) + (v6.y + v7.y);
    }
    for (; j < rem; j++) {
      int s = __shfl(idx, j);
      float2 v = h2[s * 64 + lane];
      acc0.x += v.x; acc0.y += v.y;
    }
  }
  float scale = 1.f / fmaxf((float)d, 1.f);
  float2 b = ((const float2*)bo)[lane];
  float2 o;
  o.x = fmaf(acc0.x + acc1.x, scale, b.x);
  o.y = fmaf(acc0.y + acc1.y, scale, b.y);
  ((float2*)out)[node * 64 + lane] = o;
}

extern "C" void kernel_launch(void* const* d_in, const int* in_sizes, int n_in,
                              void* d_out, int out_size, void* d_ws, size_t ws_size,
                              hipStream_t stream) {
  const float* X    = (const float*)d_in[0];   // [10000,128]
  const int*   esrc = (const int*)d_in[1];     // [320000]
  const int*   edst = (const int*)d_in[2];     // [320000]
  const float* W1   = (const float*)d_in[3];   // [128,256]
  const float* b1   = (const float*)d_in[4];
  const float* W2   = (const float*)d_in[5];   // [256,256]
  const float* b2   = (const float*)d_in[6];
  const float* Wo   = (const float*)d_in[7];   // [256,128]
  const float* bo   = (const float*)d_in[8];
  float* out = (float*)d_out;                  // [10000,128]

  // ---- workspace layout (~22.4 MB) ----
  // regionA (10.24MB): X hi/lo pair (first 5.12MB), then reused for hid pair
  // regionB (10.24MB): h1 hi/lo pair, then reused for hproj fp32
  char* p = (char*)d_ws;
  size_t needed = (size_t)NN * 256 * 4 * 2                     // regionA + regionB
                + (size_t)(32768 + 65536 + 32768) * 2 * 2      // weight hi/lo pairs
                + (size_t)(3 * NN + NE) * 4;                   // deg/offs/cursor/csr
  if (ws_size < needed) return;

  unsigned short* regA  = (unsigned short*)p;
  unsigned short* Xhi   = regA;                                // NN*128
  unsigned short* Xlo   = regA + (size_t)NN * 128;
  unsigned short* hidhi = regA;                                // NN*256 (X dead after GEMM1)
  unsigned short* hidlo = regA + (size_t)NN * 256;
  p += (size_t)NN * 256 * 4;
  unsigned short* h1hi  = (unsigned short*)p;                  // NN*256
  unsigned short* h1lo  = h1hi + (size_t)NN * 256;
  float*          hproj = (float*)h1hi;                        // NN*128 f32 (h1 dead after GEMM2)
  p += (size_t)NN * 256 * 4;
  unsigned short* W1thi = (unsigned short*)p; p += 32768 * 2;  // [256][128]
  unsigned short* W1tlo = (unsigned short*)p; p += 32768 * 2;
  unsigned short* W2thi = (unsigned short*)p; p += 65536 * 2;  // [256][256]
  unsigned short* W2tlo = (unsigned short*)p; p += 65536 * 2;
  unsigned short* Wothi = (unsigned short*)p; p += 32768 * 2;  // [128][256]
  unsigned short* Wotlo = (unsigned short*)p; p += 32768 * 2;
  int* deg    = (int*)p; p += (size_t)NN * 4;
  int* offs   = (int*)p; p += (size_t)NN * 4;
  int* cursor = (int*)p; p += (size_t)NN * 4;
  int* csr    = (int*)p; p += (size_t)NE * 4;

  // fused prep: deg=0 + X split + all weight transpose+splits (1 dispatch)
  prep_kernel<<<1250, 256, 0, stream>>>(X, Xhi, Xlo, W1, W1thi, W1tlo,
                                        W2, W2thi, W2tlo, Wo, Wothi, Wotlo, deg);

  // CSR build
  count_kernel<<<(NE + 255) / 256, 256, 0, stream>>>(edst, deg, NE);
  scan_kernel<<<1, 1024, 0, stream>>>(deg, offs, cursor);
  fill_kernel<<<(NE + 255) / 256, 256, 0, stream>>>(esrc, edst, cursor, csr, NE);

  // MLP encoder on MFMA (split-bf16, fp32-equivalent accuracy)
  mfma_gemm<1, true, 1, 128, 256><<<dim3(157, 4), 256, 0, stream>>>(
      Xhi, Xlo, W1thi, W1tlo, b1, nullptr, h1hi, h1lo, NN);
  mfma_gemm<2, true, 1, 256, 256><<<dim3(157, 4), 256, 0, stream>>>(
      h1hi, h1lo, W2thi, W2tlo, b2, nullptr, hidhi, hidlo, NN);
  // project BEFORE aggregating (mean is linear); fp32 output for aggregate
  mfma_gemm<0, false, 0, 256, 128><<<dim3(157, 2), 256, 0, stream>>>(
      hidhi, hidlo, Wothi, Wotlo, nullptr, hproj, nullptr, nullptr, NN);

  // neighbor mean over projected rows + fused bo -> d_out
  aggregate_kernel<<<(NN + 3) / 4, 256, 0, stream>>>(hproj, csr, offs, deg, bo, out, NN);
}

// Round 12
// 155.560 us; speedup vs baseline: 1.7448x; 1.1224x over previous
//
#include <hip/hip_runtime.h>
#include <hip/hip_bf16.h>

#define NN 10000
#define NE 320000
#define MLP_BLOCKS 157   // ceil(10000/64)

typedef __attribute__((ext_vector_type(8))) short bf16x8;     // MFMA A/B frag (4 VGPRs)
typedef __attribute__((ext_vector_type(4))) float f32x4;      // MFMA C/D frag
typedef __attribute__((ext_vector_type(8))) unsigned short ushort8;

// split fp32 -> bf16 hi + bf16 lo (a ~= hi + lo, residual ~2^-16 relative)
__device__ __forceinline__ void split_bf16(float a, unsigned short& hi, unsigned short& lo) {
  union { float f; unsigned int u; } v; v.f = a;
  hi = (unsigned short)(v.u >> 16);
  union { float f; unsigned int u; } h; h.u = (unsigned int)hi << 16;
  float r = a - h.f;                      // exact
  union { float f; unsigned int u; } w; w.f = r;
  lo = (unsigned short)(w.u >> 16);
}

// ---------------- prep: weight transpose+split to [N][K] hi/lo, deg=0 --------
// grid 384 x 256 = 98304 threads exactly
__global__ __launch_bounds__(256) void prep_kernel(
    const float* __restrict__ W1, unsigned short* __restrict__ W1thi, unsigned short* __restrict__ W1tlo,
    const float* __restrict__ W2, unsigned short* __restrict__ W2thi, unsigned short* __restrict__ W2tlo,
    const float* __restrict__ Wo, unsigned short* __restrict__ Wothi, unsigned short* __restrict__ Wotlo,
    int* __restrict__ deg) {
  int i = blockIdx.x * 256 + threadIdx.x;
  if (i < 2500) ((int4*)deg)[i] = make_int4(0, 0, 0, 0);       // 10000 ints
  if (i < 32768) {                       // W1 [128][256] -> W1t [256][128]
    int n = i >> 7, k = i & 127;
    unsigned short h, l; split_bf16(W1[k * 256 + n], h, l);
    W1thi[i] = h; W1tlo[i] = l;
  }
  if (i < 65536) {                       // W2 [256][256] -> W2t [256][256]
    int n = i >> 8, k = i & 255;
    unsigned short h, l; split_bf16(W2[k * 256 + n], h, l);
    W2thi[i] = h; W2tlo[i] = l;
  }
  if (i >= 65536) {                      // Wo [256][128] -> Wot [128][256]
    int o = i - 65536;
    int n = o >> 8, k = o & 255;
    unsigned short h, l; split_bf16(Wo[k * 128 + n], h, l);
    Wothi[o] = h; Wotlo[o] = l;
  }
}

// ---- one MFMA layer: A from LDS (64x[K] hi/lo, XOR-swizzled), B direct from
// global [N][K] hi/lo (L2-resident). acc = A@B with 3-MFMA split product. ----
template<int K, int NFRAG>
__device__ __forceinline__ void layer_mfma(
    const unsigned short* Ah, const unsigned short* Al,
    const unsigned short* __restrict__ Bthi, const unsigned short* __restrict__ Btlo,
    int lane, int colbase, f32x4 (&acc)[4][NFRAG]) {
  const int l15 = lane & 15, l16 = lane >> 4;
#pragma unroll
  for (int m = 0; m < 4; m++)
#pragma unroll
    for (int n = 0; n < NFRAG; n++) acc[m][n] = (f32x4){0.f, 0.f, 0.f, 0.f};
#pragma unroll 2
  for (int kk = 0; kk < K / 32; ++kk) {
    bf16x8 aH[4], aL[4], bH[NFRAG], bL[NFRAG];
#pragma unroll
    for (int m = 0; m < 4; m++) {
      int r = m * 16 + l15;
      int c = (kk * 4 + l16) ^ (r & 7);            // same involution as writer
      aH[m] = *(const bf16x8*)&Ah[r * 256 + c * 8];
      aL[m] = *(const bf16x8*)&Al[r * 256 + c * 8];
    }
#pragma unroll
    for (int n = 0; n < NFRAG; n++) {
      int col = colbase + n * 16 + l15;
      size_t off = (size_t)col * K + kk * 32 + l16 * 8;
      bH[n] = *(const bf16x8*)&Bthi[off];
      bL[n] = *(const bf16x8*)&Btlo[off];
    }
#pragma unroll
    for (int m = 0; m < 4; m++)
#pragma unroll
      for (int n = 0; n < NFRAG; n++) {
        acc[m][n] = __builtin_amdgcn_mfma_f32_16x16x32_bf16(aH[m], bH[n], acc[m][n], 0, 0, 0);
        acc[m][n] = __builtin_amdgcn_mfma_f32_16x16x32_bf16(aH[m], bL[n], acc[m][n], 0, 0, 0);
        acc[m][n] = __builtin_amdgcn_mfma_f32_16x16x32_bf16(aL[m], bH[n], acc[m][n], 0, 0, 0);
      }
  }
}

// ---- activate + split + write back into Abuf (becomes next layer's A) ----
// ACT: 1 = tanh, 2 = sigmoid(tanh)
template<int ACT>
__device__ __forceinline__ void writeback_lds(
    unsigned short* Ah, unsigned short* Al, f32x4 (&acc)[4][4],
    const float* __restrict__ bias, int lane, int colbase) {
  const int l15 = lane & 15, l16 = lane >> 4;
#pragma unroll
  for (int n = 0; n < 4; n++) {
    int col = colbase + n * 16 + l15;
    float bv = bias[col];
#pragma unroll
    for (int m = 0; m < 4; m++)
#pragma unroll
      for (int j = 0; j < 4; j++) {
        int r = m * 16 + l16 * 4 + j;              // C/D layout: row=(lane>>4)*4+j
        float v = acc[m][n][j] + bv;
        if (ACT == 1) v = tanhf(v);
        else v = 1.f / (1.f + expf(-tanhf(v)));
        unsigned short h, l; split_bf16(v, h, l);
        int c = col >> 3, e = col & 7;             // element k=col -> chunk,elem
        int idx = r * 256 + ((c ^ (r & 7)) * 8) + e;
        Ah[idx] = h; Al[idx] = l;
      }
  }
}

// ---------------- megakernel: 3-layer MLP fused (+ count as extra blocks) ----
// blocks [0,157): one 64-row panel each; A resident in LDS (64KB) across layers
// blocks [157,1407): edge-degree count (deg zeroed by prep, a prior dispatch)
__global__ __launch_bounds__(256) void mega_kernel(
    const float* __restrict__ X,
    const unsigned short* __restrict__ W1thi, const unsigned short* __restrict__ W1tlo,
    const float* __restrict__ b1,
    const unsigned short* __restrict__ W2thi, const unsigned short* __restrict__ W2tlo,
    const float* __restrict__ b2,
    const unsigned short* __restrict__ Wothi, const unsigned short* __restrict__ Wotlo,
    float* __restrict__ hproj,
    const int* __restrict__ edst, int* __restrict__ deg) {
  if (blockIdx.x >= MLP_BLOCKS) {
    int e = (blockIdx.x - MLP_BLOCKS) * 256 + threadIdx.x;
    if (e < NE) atomicAdd(&deg[edst[e]], 1);
    return;
  }
  __shared__ unsigned short Ah[64 * 256], Al[64 * 256];   // 32KB + 32KB
  const int tid = threadIdx.x, lane = tid & 63, w = tid >> 6;
  const int row0 = blockIdx.x * 64;

  // stage X fp32 [64][128] -> split hi/lo into Abuf chunks 0..15 per row
#pragma unroll
  for (int it = 0; it < 4; ++it) {
    int slot = it * 256 + tid;                    // 1024 chunk-slots
    int r = slot >> 4, c = slot & 15;
    int gr = row0 + r; if (gr > NN - 1) gr = NN - 1;
    const float* xp = &X[(size_t)gr * 128 + c * 8];
    float4 x0 = *(const float4*)xp;
    float4 x1 = *(const float4*)(xp + 4);
    unsigned short h0, l0, h1, l1, h2, l2, h3, l3;
    unsigned short h4, l4, h5, l5, h6, l6, h7, l7;
    split_bf16(x0.x, h0, l0); split_bf16(x0.y, h1, l1);
    split_bf16(x0.z, h2, l2); split_bf16(x0.w, h3, l3);
    split_bf16(x1.x, h4, l4); split_bf16(x1.y, h5, l5);
    split_bf16(x1.z, h6, l6); split_bf16(x1.w, h7, l7);
    ushort8 h, l;
    h[0] = h0; h[1] = h1; h[2] = h2; h[3] = h3;
    h[4] = h4; h[5] = h5; h[6] = h6; h[7] = h7;
    l[0] = l0; l[1] = l1; l[2] = l2; l[3] = l3;
    l[4] = l4; l[5] = l5; l[6] = l6; l[7] = l7;
    int base = r * 256 + ((c ^ (r & 7)) * 8);
    *(ushort8*)&Ah[base] = h;
    *(ushort8*)&Al[base] = l;
  }
  __syncthreads();

  { // layer 1: K=128 -> N=256, tanh
    f32x4 acc[4][4];
    layer_mfma<128, 4>(Ah, Al, W1thi, W1tlo, lane, w * 64, acc);
    __syncthreads();                               // all reads of A done
    writeback_lds<1>(Ah, Al, acc, b1, lane, w * 64);
    __syncthreads();
  }
  { // layer 2: K=256 -> N=256, sigmoid(tanh)
    f32x4 acc[4][4];
    layer_mfma<256, 4>(Ah, Al, W2thi, W2tlo, lane, w * 64, acc);
    __syncthreads();
    writeback_lds<2>(Ah, Al, acc, b2, lane, w * 64);
    __syncthreads();
  }
  { // layer 3: K=256 -> N=128 (wave covers 32 cols), no bias -> global hproj
    f32x4 acc[4][2];
    layer_mfma<256, 2>(Ah, Al, Wothi, Wotlo, lane, w * 32, acc);
    const int l15 = lane & 15, l16 = lane >> 4;
#pragma unroll
    for (int n = 0; n < 2; n++) {
      int col = w * 32 + n * 16 + l15;
#pragma unroll
      for (int m = 0; m < 4; m++)
#pragma unroll
        for (int j = 0; j < 4; j++) {
          int grow = row0 + m * 16 + l16 * 4 + j;
          if (grow < NN) hproj[(size_t)grow * 128 + col] = acc[m][n][j];
        }
    }
  }
}

// 1-block exclusive scan: 1024 thr x 10 nodes, shfl wave-scan, 3 barriers
__global__ __launch_bounds__(1024) void scan_kernel(
    const int* __restrict__ deg, int* __restrict__ offs, int* __restrict__ cursor) {
  __shared__ int wsum[16];
  int t = threadIdx.x;
  int base = t * 10;
  int loc[10];
  int s = 0;
  if (base < NN) {
#pragma unroll
    for (int i = 0; i < 10; i++) {
      int idx = base + i;
      int v = (idx < NN) ? deg[idx] : 0;
      loc[i] = s; s += v;
    }
  }
  int lane = t & 63, w = t >> 6;
  int incl = s;
  for (int off = 1; off < 64; off <<= 1) {
    int u = __shfl_up(incl, off, 64);
    if (lane >= off) incl += u;
  }
  if (lane == 63) wsum[w] = incl;
  __syncthreads();
  if (t == 0) {
    int c = 0;
#pragma unroll
    for (int i = 0; i < 16; i++) { int v = wsum[i]; wsum[i] = c; c += v; }
  }
  __syncthreads();
  int ex = wsum[w] + incl - s;
  if (base < NN) {
#pragma unroll
    for (int i = 0; i < 10; i++) {
      int idx = base + i;
      if (idx < NN) { int o = ex + loc[i]; offs[idx] = o; cursor[idx] = o; }
    }
  }
}

__global__ void fill_kernel(const int* __restrict__ src, const int* __restrict__ dst,
                            int* __restrict__ cursor, int* __restrict__ csr, int n) {
  int i = blockIdx.x * blockDim.x + threadIdx.x;
  if (i < n) {
    int d = dst[i];
    int pos = atomicAdd(&cursor[d], 1);
    csr[pos] = src[i];
  }
}

// ---------------- segment mean over PROJECTED rows (128 cols) + bias -> out
__global__ __launch_bounds__(256) void aggregate_kernel(
    const float* __restrict__ hproj, const int* __restrict__ csr,
    const int* __restrict__ offs, const int* __restrict__ deg,
    const float* __restrict__ bo, float* __restrict__ out, int n_nodes) {
  int wave = threadIdx.x >> 6;
  int lane = threadIdx.x & 63;
  int node = blockIdx.x * 4 + wave;
  if (node >= n_nodes) return;
  int start = offs[node];
  int d = deg[node];
  const float2* h2 = (const float2*)hproj;
  float2 acc0 = make_float2(0.f, 0.f), acc1 = make_float2(0.f, 0.f);
  for (int t0 = 0; t0 < d; t0 += 64) {
    int rem = d - t0; if (rem > 64) rem = 64;
    int idx = (lane < rem) ? csr[start + t0 + lane] : 0;
    int j = 0;
    for (; j + 8 <= rem; j += 8) {
      int s0 = __shfl(idx, j + 0), s1 = __shfl(idx, j + 1);
      int s2 = __shfl(idx, j + 2), s3 = __shfl(idx, j + 3);
      int s4 = __shfl(idx, j + 4), s5 = __shfl(idx, j + 5);
      int s6 = __shfl(idx, j + 6), s7 = __shfl(idx, j + 7);
      float2 v0 = h2[s0 * 64 + lane], v1 = h2[s1 * 64 + lane];
      float2 v2 = h2[s2 * 64 + lane], v3 = h2[s3 * 64 + lane];
      float2 v4 = h2[s4 * 64 + lane], v5 = h2[s5 * 64 + lane];
      float2 v6 = h2[s6 * 64 + lane], v7 = h2[s7 * 64 + lane];
      acc0.x += (v0.x + v1.x) + (v2.x + v3.x);
      acc0.y += (v0.y + v1.y) + (v2.y + v3.y);
      acc1.x += (v4.x + v5.x) + (v6.x + v7.x);
      acc1.y += (v4.y + v5.y) + (v6.y + v7.y);
    }
    for (; j < rem; j++) {
      int s = __shfl(idx, j);
      float2 v = h2[s * 64 + lane];
      acc0.x += v.x; acc0.y += v.y;
    }
  }
  float scale = 1.f / fmaxf((float)d, 1.f);
  float2 b = ((const float2*)bo)[lane];
  float2 o;
  o.x = fmaf(acc0.x + acc1.x, scale, b.x);
  o.y = fmaf(acc0.y + acc1.y, scale, b.y);
  ((float2*)out)[node * 64 + lane] = o;
}

extern "C" void kernel_launch(void* const* d_in, const int* in_sizes, int n_in,
                              void* d_out, int out_size, void* d_ws, size_t ws_size,
                              hipStream_t stream) {
  const float* X    = (const float*)d_in[0];   // [10000,128]
  const int*   esrc = (const int*)d_in[1];     // [320000]
  const int*   edst = (const int*)d_in[2];     // [320000]
  const float* W1   = (const float*)d_in[3];   // [128,256]
  const float* b1   = (const float*)d_in[4];
  const float* W2   = (const float*)d_in[5];   // [256,256]
  const float* b2   = (const float*)d_in[6];
  const float* Wo   = (const float*)d_in[7];   // [256,128]
  const float* bo   = (const float*)d_in[8];
  float* out = (float*)d_out;                  // [10000,128]

  // workspace: hproj (5.12MB) + weight hi/lo (512KB) + CSR ints (~1.4MB)
  char* p = (char*)d_ws;
  size_t needed = (size_t)NN * 128 * 4
                + (size_t)(32768 + 65536 + 32768) * 2 * 2
                + (size_t)(3 * NN + NE) * 4;
  if (ws_size < needed) return;

  float* hproj = (float*)p;                   p += (size_t)NN * 128 * 4;
  unsigned short* W1thi = (unsigned short*)p; p += 32768 * 2;
  unsigned short* W1tlo = (unsigned short*)p; p += 32768 * 2;
  unsigned short* W2thi = (unsigned short*)p; p += 65536 * 2;
  unsigned short* W2tlo = (unsigned short*)p; p += 65536 * 2;
  unsigned short* Wothi = (unsigned short*)p; p += 32768 * 2;
  unsigned short* Wotlo = (unsigned short*)p; p += 32768 * 2;
  int* deg    = (int*)p; p += (size_t)NN * 4;
  int* offs   = (int*)p; p += (size_t)NN * 4;
  int* cursor = (int*)p; p += (size_t)NN * 4;
  int* csr    = (int*)p; p += (size_t)NE * 4;

  // 1) weights transpose+split, deg=0
  prep_kernel<<<384, 256, 0, stream>>>(W1, W1thi, W1tlo, W2, W2thi, W2tlo,
                                       Wo, Wothi, Wotlo, deg);
  // 2) fused 3-layer MLP + projection (blocks 0..156) and degree count (rest)
  mega_kernel<<<MLP_BLOCKS + (NE + 255) / 256, 256, 0, stream>>>(
      X, W1thi, W1tlo, b1, W2thi, W2tlo, b2, Wothi, Wotlo, hproj, edst, deg);
  // 3) offsets
  scan_kernel<<<1, 1024, 0, stream>>>(deg, offs, cursor);
  // 4) CSR fill
  fill_kernel<<<(NE + 255) / 256, 256, 0, stream>>>(esrc, edst, cursor, csr, NE);
  // 5) neighbor mean + fused bo -> d_out
  aggregate_kernel<<<(NN + 3) / 4, 256, 0, stream>>>(hproj, csr, offs, deg, bo, out, NN);
}